// Round 10
// baseline (142.850 us; speedup 1.0000x reference)
//
#include <hip/hip_runtime.h>
#include <hip/hip_bf16.h>

#define C_IN    64
#define C_OUT   128
#define HH      112
#define WW      112
#define NB      16
#define KTOT    576      // C_IN * 9
#define NSTEPS  36       // KTOT / 16
#define NPIX    (HH*WW)  // 12544
#define PH      114      // padded spatial dim
#define PPIX    (PH*PH)  // 12996
#define XT_OFF  147456   // bytes: pw occupies [0, 147456)
#define XT_BYTES ((size_t)NB * PPIX * C_IN * 2)
// slab tiling: block = 64 c_out x 16-row band; iterate 4 tiles of 16h x 32w (last 16w)
#define A_BYTES 73728    // 36 t * 2 mt * 64 lanes * 16 B
#define B_PITCH 34       // halo cols
#define B_RECS  612      // 18 rows * 34 cols
#define B_SLOT  81920    // 10 rounds * 8192 (78336 used + slack)
// fallback tiling (round-2 kernel)
#define TY      8
#define TX      16
#define HALO_X  18
#define HALO_P  180
#define TILES_X 7
#define NTILES  98

typedef __bf16 bf16x8 __attribute__((ext_vector_type(8)));
typedef float  f32x16 __attribute__((ext_vector_type(16)));

static __device__ __forceinline__ unsigned short f2bf(float v) {
    unsigned int u = __builtin_bit_cast(unsigned int, v);
    u = u + 0x7fffu + ((u >> 16) & 1u);   // RNE
    return (unsigned short)(u >> 16);
}

// ---------------- pack spW = weight*mask into bf16 MFMA A-fragments ----------------
// pw_frag[t][mt][lane] = 16 B (8 bf16); k_log(t,g,e)=t*16+g*8+e; ij=k_log>>6, c=k_log&63; k_orig=c*9+ij
__global__ __launch_bounds__(256) void pack_w_kernel(
        const float* __restrict__ weight, const float* __restrict__ mask,
        unsigned short* __restrict__ pw) {
    int t  = blockIdx.x;           // 0..35
    int mt = threadIdx.x >> 6;     // 0..3
    int l  = threadIdx.x & 63;
    int g  = l >> 5;
    int m  = mt * 32 + (l & 31);
    unsigned int words[4];
    #pragma unroll
    for (int ew = 0; ew < 4; ++ew) {
        unsigned int w2[2];
        #pragma unroll
        for (int h = 0; h < 2; ++h) {
            int e    = ew * 2 + h;
            int klog = t * 16 + g * 8 + e;
            int ij   = klog >> 6;
            int c    = klog & 63;
            int ko   = c * 9 + ij;
            w2[h] = f2bf(weight[m * KTOT + ko] * mask[m * KTOT + ko]);
        }
        words[ew] = w2[0] | (w2[1] << 16);
    }
    uint4 o4; o4.x = words[0]; o4.y = words[1]; o4.z = words[2]; o4.w = words[3];
    ((uint4*)pw)[(t * 4 + mt) * 64 + l] = o4;
}

// ---------------- pre-pass: x [b][c][h][w] fp32 -> xT [b][hp][wp][c] bf16, zero-padded ----------------
__global__ __launch_bounds__(256) void transpose_x_kernel(
        const float* __restrict__ x, unsigned short* __restrict__ xT) {
    const int b  = blockIdx.y;
    const int pp = blockIdx.x * 256 + threadIdx.x;
    if (pp >= PPIX) return;
    const int hp = pp / PH, wp = pp - hp * PH;
    const int gh = hp - 1, gw = wp - 1;
    const bool valid = (unsigned)gh < (unsigned)HH && (unsigned)gw < (unsigned)WW;
    const float* src = x + (size_t)b * C_IN * (HH * WW) + (gh * WW + gw);
    uint4* dst = (uint4*)(xT + ((size_t)b * PPIX + pp) * C_IN);
    #pragma unroll
    for (int cb = 0; cb < 8; ++cb) {
        unsigned int w4[4];
        #pragma unroll
        for (int h = 0; h < 4; ++h) {
            float v0 = valid ? src[(size_t)(cb * 8 + h * 2    ) * (HH * WW)] : 0.0f;
            float v1 = valid ? src[(size_t)(cb * 8 + h * 2 + 1) * (HH * WW)] : 0.0f;
            w4[h] = (unsigned)f2bf(v0) | ((unsigned)f2bf(v1) << 16);
        }
        uint4 o; o.x = w4[0]; o.y = w4[1]; o.z = w4[2]; o.w = w4[3];
        dst[cb] = o;
    }
}

// ---------------- main conv: A-resident slab, 2Mx2N waves, overlapped B staging ----------------
// Block (512 thr, 8 waves) = M-half mh (64 c_out) x one 16-row band of one image.
// A (73.7 KB) staged in LDS once. Iterate 4 tiles of 16h x 32w (it=3: 16w):
//   compute(it) -> barrier -> issue stage(it+1) -> stores(it) overlap -> barrier.
// Wave = both M-tiles x 2 N-tiles (rows 2w,2w+1 of the tile, 32 cols).
__global__ __launch_bounds__(512, 2) void sparse_conv_slab_kernel(
        const unsigned short* __restrict__ xT, const unsigned short* __restrict__ pw,
        const float* __restrict__ bias, float* __restrict__ out) {
    __shared__ __align__(16) unsigned char smem[A_BYTES + B_SLOT];   // 155648 B
    unsigned char* As = smem;
    unsigned char* Bs = smem + A_BYTES;

    // XCD-bijective swizzle: 224 % 8 == 0; XCD k gets 28 contiguous bids = 2 images
    const int bid  = (blockIdx.x & 7) * 28 + (blockIdx.x >> 3);
    const int b    = bid / 14;
    const int rem  = bid % 14;
    const int mh   = rem & 1;
    const int band = rem >> 1;          // 0..6
    const int h0   = band * 16;         // first output row (also padded top halo row)
    const int tid  = threadIdx.x;
    const int wave = tid >> 6, l = tid & 63;
    const int g = l >> 5, ln = l & 31;

    const char* xTb = (const char*)xT + (size_t)b * PPIX * (C_IN * 2);

    // ---- stage A once: 9 rounds of global_load_lds (73728 B exact, linear) ----
    {
        const char* pwb = (const char*)pw;
        #pragma unroll
        for (int r = 0; r < 9; ++r) {
            int c  = r * 512 + tid;          // c = (t*2+mt)*64 + lane
            int t  = c >> 7;
            int mt = (c >> 6) & 1;
            int ll = c & 63;
            const char* gp = pwb + (size_t)((t * 4 + mh * 2 + mt) * 64 + ll) * 16;
            char* lp = (char*)As + r * 8192 + wave * 1024;   // + lane*16 by HW
            __builtin_amdgcn_global_load_lds(
                (const __attribute__((address_space(1))) void*)gp,
                (__attribute__((address_space(3))) void*)lp, 16, 0, 0);
        }
    }

    // ---- B staging: halo 18 rows x 34 cols at padded (h0, it*32); swizzled source ----
    auto STAGE = [&](int it) {
        #pragma unroll
        for (int r = 0; r < 10; ++r) {
            int chunk = r * 512 + tid;
            if (chunk > B_RECS * 8 - 1) chunk = B_RECS * 8 - 1;   // dup tail, dest linear
            int p = chunk >> 3, s = chunk & 7;
            int yy = p / B_PITCH, xx = p - yy * B_PITCH;
            const char* gp = xTb + (size_t)((h0 + yy) * PH + (it * 32 + xx)) * (C_IN * 2)
                                 + (((s ^ p) & 7) << 4);
            char* lp = (char*)Bs + r * 8192 + wave * 1024;
            __builtin_amdgcn_global_load_lds(
                (const __attribute__((address_space(1))) void*)gp,
                (__attribute__((address_space(3))) void*)lp, 16, 0, 0);
        }
    };

    // bias by accumulator slot, o = mh*64 + mt*32 + mloc
    float bv[2][16];
    #pragma unroll
    for (int mt = 0; mt < 2; ++mt)
        #pragma unroll
        for (int r = 0; r < 16; ++r) {
            int mloc = (r & 3) + 8 * (r >> 2) + 4 * g;
            bv[mt][r] = bias[mh * 64 + mt * 32 + mloc];
        }

    STAGE(0);
    __syncthreads();   // drain A + B0

    const size_t outb = (size_t)b * C_OUT * NPIX;

    #pragma unroll 1
    for (int it = 0; it < 4; ++it) {
        const bool full = (it < 3);
        // lane pixel map: full tile: wave rows {2w,2w+1} x cols ln(0..31);
        // it=3 (16 wide): py = 2w + (ln>>4), px = ln&15, single N-tile
        const int py3 = 2 * wave + (ln >> 4);
        const int px3 = ln & 15;

        f32x16 acc[2][2];
        #pragma unroll
        for (int mt = 0; mt < 2; ++mt)
            #pragma unroll
            for (int ntp = 0; ntp < 2; ++ntp)
                #pragma unroll
                for (int r = 0; r < 16; ++r) acc[mt][ntp][r] = bv[mt][r];

        if (full) {
            #pragma unroll
            for (int t = 0; t < NSTEPS; ++t) {
                const int ij = t >> 2, cs = t & 3;
                const int di = ij / 3, dj = ij - di * 3;
                const int jb = cs * 2 + g;
                bf16x8 a0 = __builtin_bit_cast(bf16x8,
                    *(const uint4*)(As + ((t * 2 + 0) * 64 + l) * 16));
                bf16x8 a1 = __builtin_bit_cast(bf16x8,
                    *(const uint4*)(As + ((t * 2 + 1) * 64 + l) * 16));
                #pragma unroll
                for (int ntp = 0; ntp < 2; ++ntp) {
                    const int Pa = (2 * wave + ntp + di) * B_PITCH + (ln + dj);
                    bf16x8 bb = __builtin_bit_cast(bf16x8,
                        *(const uint4*)(Bs + Pa * 128 + (((jb ^ Pa) & 7) << 4)));
                    acc[0][ntp] = __builtin_amdgcn_mfma_f32_32x32x16_bf16(a0, bb, acc[0][ntp], 0, 0, 0);
                    acc[1][ntp] = __builtin_amdgcn_mfma_f32_32x32x16_bf16(a1, bb, acc[1][ntp], 0, 0, 0);
                }
            }
        } else {
            #pragma unroll
            for (int t = 0; t < NSTEPS; ++t) {
                const int ij = t >> 2, cs = t & 3;
                const int di = ij / 3, dj = ij - di * 3;
                const int jb = cs * 2 + g;
                bf16x8 a0 = __builtin_bit_cast(bf16x8,
                    *(const uint4*)(As + ((t * 2 + 0) * 64 + l) * 16));
                bf16x8 a1 = __builtin_bit_cast(bf16x8,
                    *(const uint4*)(As + ((t * 2 + 1) * 64 + l) * 16));
                const int Pa = (py3 + di) * B_PITCH + (px3 + dj);
                bf16x8 bb = __builtin_bit_cast(bf16x8,
                    *(const uint4*)(Bs + Pa * 128 + (((jb ^ Pa) & 7) << 4)));
                acc[0][0] = __builtin_amdgcn_mfma_f32_32x32x16_bf16(a0, bb, acc[0][0], 0, 0, 0);
                acc[1][0] = __builtin_amdgcn_mfma_f32_32x32x16_bf16(a1, bb, acc[1][0], 0, 0, 0);
            }
        }

        __syncthreads();               // all waves done reading Bs
        if (it < 3) STAGE(it + 1);     // async issue next halo

        // ---- stores overlap staging. C/D col=lane&31 (pixel), row=(r&3)+8*(r>>2)+4*g ----
        if (full) {
            #pragma unroll
            for (int mt = 0; mt < 2; ++mt)
                #pragma unroll
                for (int r = 0; r < 16; ++r) {
                    int mloc = (r & 3) + 8 * (r >> 2) + 4 * g;
                    int o = mh * 64 + mt * 32 + mloc;
                    #pragma unroll
                    for (int ntp = 0; ntp < 2; ++ntp) {
                        int row = h0 + 2 * wave + ntp;
                        out[outb + (size_t)o * NPIX + row * WW + it * 32 + ln]
                            = acc[mt][ntp][r];
                    }
                }
        } else {
            #pragma unroll
            for (int mt = 0; mt < 2; ++mt)
                #pragma unroll
                for (int r = 0; r < 16; ++r) {
                    int mloc = (r & 3) + 8 * (r >> 2) + 4 * g;
                    int o = mh * 64 + mt * 32 + mloc;
                    out[outb + (size_t)o * NPIX + (h0 + py3) * WW + 96 + px3]
                        = acc[mt][0][r];
                }
        }
        __syncthreads();   // stage(it+1) drained (compiler vmcnt before barrier)
    }
}

// ---------------- fallback (round-2 kernel) if ws too small for xT ----------------
__global__ __launch_bounds__(256, 4) void sparse_conv_fb_kernel(
        const float* __restrict__ x, const unsigned short* __restrict__ pw,
        const float* __restrict__ bias, float* __restrict__ out) {
    __shared__ __align__(16) unsigned short xs[HALO_P * C_IN];

    const int bid = blockIdx.x;
    const int b   = bid / NTILES;
    const int t98 = bid % NTILES;
    const int tyi = t98 / TILES_X;
    const int txi = t98 % TILES_X;
    const int h0  = tyi * TY, w0 = txi * TX;
    const int tid = threadIdx.x;

    const float* xb = x + (size_t)b * C_IN * HH * WW;
    {
        const int p  = tid;
        const bool act = p < HALO_P;
        int yy = p / HALO_X;
        int xx = p - yy * HALO_X;
        int gh = h0 + yy - 1, gw = w0 + xx - 1;
        const bool valid = act && (unsigned)gh < (unsigned)HH && (unsigned)gw < (unsigned)WW;
        const float* bp = xb + (gh * WW + gw);
        float v[C_IN];
        #pragma unroll
        for (int c = 0; c < C_IN; ++c)
            v[c] = valid ? bp[c * (HH * WW)] : 0.0f;
        if (act) {
            char* xc = (char*)xs + p * (C_IN * 2);
            #pragma unroll
            for (int j = 0; j < 8; ++j) {
                bf16x8 bvv;
                #pragma unroll
                for (int e = 0; e < 8; ++e) bvv[e] = (__bf16)v[j * 8 + e];
                *(uint4*)(xc + (((j ^ p) & 7) << 4)) = __builtin_bit_cast(uint4, bvv);
            }
        }
    }
    __syncthreads();

    const int wave = tid >> 6, l = tid & 63;
    const int wm = wave >> 1, wn = wave & 1;
    const int g  = l >> 5,  ln = l & 31;

    int P0[2];
    #pragma unroll
    for (int ntp = 0; ntp < 2; ++ntp) {
        int pt = wn * 64 + ntp * 32 + ln;
        P0[ntp] = (pt >> 4) * HALO_X + (pt & 15);
    }

    f32x16 acc[2][2];
    #pragma unroll
    for (int i = 0; i < 2; ++i)
        #pragma unroll
        for (int jq = 0; jq < 2; ++jq)
            #pragma unroll
            for (int q = 0; q < 16; ++q) acc[i][jq][q] = 0.0f;

    const uint4* __restrict__ pwv = (const uint4*)pw;

    #pragma unroll 1
    for (int ij = 0; ij < 9; ++ij) {
        const int di = ij / 3;
        const int dj = ij - di * 3;
        const int P0a = P0[0] + di * HALO_X + dj;
        const int P1a = P0[1] + di * HALO_X + dj;
        #pragma unroll
        for (int cs = 0; cs < 4; ++cs) {
            const int t = ij * 4 + cs;
            bf16x8 a0 = __builtin_bit_cast(bf16x8, pwv[(t * 4 + wm * 2 + 0) * 64 + l]);
            bf16x8 a1 = __builtin_bit_cast(bf16x8, pwv[(t * 4 + wm * 2 + 1) * 64 + l]);
            const int jb = cs * 2 + g;
            bf16x8 b0 = __builtin_bit_cast(bf16x8,
                *(const uint4*)((const char*)xs + P0a * (C_IN * 2) + (((jb ^ P0a) & 7) << 4)));
            bf16x8 b1 = __builtin_bit_cast(bf16x8,
                *(const uint4*)((const char*)xs + P1a * (C_IN * 2) + (((jb ^ P1a) & 7) << 4)));
            acc[0][0] = __builtin_amdgcn_mfma_f32_32x32x16_bf16(a0, b0, acc[0][0], 0, 0, 0);
            acc[0][1] = __builtin_amdgcn_mfma_f32_32x32x16_bf16(a0, b1, acc[0][1], 0, 0, 0);
            acc[1][0] = __builtin_amdgcn_mfma_f32_32x32x16_bf16(a1, b0, acc[1][0], 0, 0, 0);
            acc[1][1] = __builtin_amdgcn_mfma_f32_32x32x16_bf16(a1, b1, acc[1][1], 0, 0, 0);
        }
    }

    const size_t outb = (size_t)b * C_OUT * HH * WW;
    #pragma unroll
    for (int mtp = 0; mtp < 2; ++mtp) {
        #pragma unroll
        for (int r = 0; r < 16; ++r) {
            int mloc = (r & 3) + 8 * (r >> 2) + 4 * g;
            int o = (wm * 2 + mtp) * 32 + mloc;
            float bvv = bias[o];
            #pragma unroll
            for (int ntp = 0; ntp < 2; ++ntp) {
                int p  = wn * 64 + ntp * 32 + ln;
                int gh = h0 + (p >> 4), gw = w0 + (p & 15);
                out[outb + ((size_t)o * HH + gh) * WW + gw] = acc[mtp][ntp][r] + bvv;
            }
        }
    }
}

extern "C" void kernel_launch(void* const* d_in, const int* in_sizes, int n_in,
                              void* d_out, int out_size, void* d_ws, size_t ws_size,
                              hipStream_t stream) {
    const float* x    = (const float*)d_in[0];
    const float* w    = (const float*)d_in[1];
    const float* mk   = (const float*)d_in[2];
    const float* bs   = (const float*)d_in[3];
    float* out        = (float*)d_out;
    unsigned short* pw = (unsigned short*)d_ws;   // [0, 147456)

    pack_w_kernel<<<dim3(NSTEPS), dim3(256), 0, stream>>>(w, mk, pw);

    if (ws_size >= (size_t)XT_OFF + XT_BYTES + 4096) {
        unsigned short* xT = (unsigned short*)((char*)d_ws + XT_OFF);
        transpose_x_kernel<<<dim3((PPIX + 255) / 256, NB), dim3(256), 0, stream>>>(x, xT);
        sparse_conv_slab_kernel<<<dim3(224), dim3(512), 0, stream>>>(xT, pw, bs, out);
    } else {
        sparse_conv_fb_kernel<<<dim3(NB * NTILES), dim3(256), 0, stream>>>(x, pw, bs, out);
    }
}

// Round 11
// 72.239 us; speedup vs baseline: 1.9775x; 1.9775x over previous
//
#include <hip/hip_runtime.h>
#include <hip/hip_bf16.h>

#define C_IN    64
#define C_OUT   128
#define HH      112
#define WW      112
#define NB      16
#define KTOT    576      // C_IN * 9
#define NSTEPS  36       // KTOT / 16
#define NPIX    (HH*WW)  // 12544
#define PH      114      // padded spatial dim
#define PPIX    (PH*PH)  // 12996
#define XT_OFF  147456   // bytes: pw occupies [0, 147456)
#define XT_BYTES ((size_t)NB * PPIX * C_IN * 2)
// band tiling: block (448 thr, 7 waves) = 64 c_out x 14-row band; 7 iters of 14h x 16w
#define BAND_H  14
#define BH_X    18       // halo cols per 16-wide tile
#define B_RECS  288      // 16 halo rows * 18 cols
#define A_BYTES 73728    // 36 t * 2 mt * 64 lanes * 16 B
#define B_BYTES 36864    // 288 recs * 128 B
// fallback tiling (round-2 kernel)
#define TY      8
#define TX      16
#define HALO_X  18
#define HALO_P  180
#define TILES_X 7
#define NTILES  98

typedef __bf16 bf16x8 __attribute__((ext_vector_type(8)));
typedef float  f32x16 __attribute__((ext_vector_type(16)));

static __device__ __forceinline__ unsigned short f2bf(float v) {
    unsigned int u = __builtin_bit_cast(unsigned int, v);
    u = u + 0x7fffu + ((u >> 16) & 1u);   // RNE
    return (unsigned short)(u >> 16);
}

#define GLOAD_LDS(gp, lp) __builtin_amdgcn_global_load_lds( \
    (const __attribute__((address_space(1))) void*)(gp),    \
    (__attribute__((address_space(3))) void*)(lp), 16, 0, 0)

// ---------------- pack spW = weight*mask into bf16 MFMA A-fragments ----------------
// pw_frag[t][mt][lane] = 16 B (8 bf16); k_log(t,g,e)=t*16+g*8+e; ij=k_log>>6, c=k_log&63; k_orig=c*9+ij
__global__ __launch_bounds__(256) void pack_w_kernel(
        const float* __restrict__ weight, const float* __restrict__ mask,
        unsigned short* __restrict__ pw) {
    int t  = blockIdx.x;           // 0..35
    int mt = threadIdx.x >> 6;     // 0..3
    int l  = threadIdx.x & 63;
    int g  = l >> 5;
    int m  = mt * 32 + (l & 31);
    unsigned int words[4];
    #pragma unroll
    for (int ew = 0; ew < 4; ++ew) {
        unsigned int w2[2];
        #pragma unroll
        for (int h = 0; h < 2; ++h) {
            int e    = ew * 2 + h;
            int klog = t * 16 + g * 8 + e;
            int ij   = klog >> 6;
            int c    = klog & 63;
            int ko   = c * 9 + ij;
            w2[h] = f2bf(weight[m * KTOT + ko] * mask[m * KTOT + ko]);
        }
        words[ew] = w2[0] | (w2[1] << 16);
    }
    uint4 o4; o4.x = words[0]; o4.y = words[1]; o4.z = words[2]; o4.w = words[3];
    ((uint4*)pw)[(t * 4 + mt) * 64 + l] = o4;
}

// ---------------- pre-pass: x [b][c][h][w] fp32 -> xT [b][hp][wp][c] bf16, zero-padded ----------------
__global__ __launch_bounds__(256) void transpose_x_kernel(
        const float* __restrict__ x, unsigned short* __restrict__ xT) {
    const int b  = blockIdx.y;
    const int pp = blockIdx.x * 256 + threadIdx.x;
    if (pp >= PPIX) return;
    const int hp = pp / PH, wp = pp - hp * PH;
    const int gh = hp - 1, gw = wp - 1;
    const bool valid = (unsigned)gh < (unsigned)HH && (unsigned)gw < (unsigned)WW;
    const float* src = x + (size_t)b * C_IN * (HH * WW) + (gh * WW + gw);
    uint4* dst = (uint4*)(xT + ((size_t)b * PPIX + pp) * C_IN);
    #pragma unroll
    for (int cb = 0; cb < 8; ++cb) {
        unsigned int w4[4];
        #pragma unroll
        for (int h = 0; h < 4; ++h) {
            float v0 = valid ? src[(size_t)(cb * 8 + h * 2    ) * (HH * WW)] : 0.0f;
            float v1 = valid ? src[(size_t)(cb * 8 + h * 2 + 1) * (HH * WW)] : 0.0f;
            w4[h] = (unsigned)f2bf(v0) | ((unsigned)f2bf(v1) << 16);
        }
        uint4 o; o.x = w4[0]; o.y = w4[1]; o.z = w4[2]; o.w = w4[3];
        dst[cb] = o;
    }
}

// ---------------- main conv: A-resident band, lean waves, double-buffered B ----------------
// Block (448 thr, 7 waves) = M-half mh (64 c_out) x one 14-row band. A (73.7 KB) in LDS once.
// 7 iters over 14h x 16w tiles: issue STAGE(it+1)->buf^1, compute it (36 K-steps:
// 2 A ds_reads + 1 B ds_read + 2 MFMA), stores, barrier (drains stage). acc[2] = 32 VGPR.
__global__ __launch_bounds__(448, 1) void sparse_conv_band_kernel(
        const unsigned short* __restrict__ xT, const unsigned short* __restrict__ pw,
        const float* __restrict__ bias, float* __restrict__ out) {
    __shared__ __align__(16) unsigned char smem[A_BYTES + 2 * B_BYTES];   // 147456 B
    unsigned char* As  = smem;
    unsigned char* Bs0 = smem + A_BYTES;
    unsigned char* Bs1 = smem + A_BYTES + B_BYTES;

    // XCD-bijective swizzle: 256 % 8 == 0; XCD k gets 32 contiguous bids = 2 images
    const int bid  = (blockIdx.x & 7) * 32 + (blockIdx.x >> 3);
    const int b    = bid >> 4;
    const int rem  = bid & 15;
    const int mh   = rem & 1;        // adjacent bids share (b,band) -> same-XCD L2 reuse
    const int band = rem >> 1;       // 0..7
    const int h0   = band * BAND_H;
    const int tid  = threadIdx.x;
    const int wave = tid >> 6, l = tid & 63;
    const int g = l >> 5, ln = l & 31;

    const char* xTb = (const char*)xT + (size_t)b * PPIX * (C_IN * 2);

    // ---- stage A once: 10 full rounds + wave-uniform tail (waves 0-1) ----
    {
        const char* pwb = (const char*)pw;
        #pragma unroll
        for (int r = 0; r < 10; ++r) {
            int c  = r * 448 + tid;          // c = (t*2+mt)*64 + lane
            int t  = c >> 7;
            int mt = (c >> 6) & 1;
            int ll = c & 63;
            const char* gp = pwb + (size_t)((t * 4 + mh * 2 + mt) * 64 + ll) * 16;
            GLOAD_LDS(gp, (char*)As + r * 7168 + wave * 1024);
        }
        if (tid < 128) {                     // waves 0,1 exactly (wave-uniform)
            int c  = 10 * 448 + tid;         // 4480..4607
            int t  = c >> 7;
            int mt = (c >> 6) & 1;
            int ll = c & 63;
            const char* gp = pwb + (size_t)((t * 4 + mh * 2 + mt) * 64 + ll) * 16;
            GLOAD_LDS(gp, (char*)As + 10 * 7168 + wave * 1024);
        }
    }

    // ---- B staging: halo 16 rows x 18 cols at padded (h0, it*16); swizzled source ----
    auto STAGE = [&](int it, unsigned char* dst) {
        const int w0 = it * 16;
        #pragma unroll
        for (int r = 0; r < 5; ++r) {
            int chunk = r * 448 + tid;
            int p = chunk >> 3, s = chunk & 7;
            int yy = p / BH_X, xx = p - yy * BH_X;
            const char* gp = xTb + (size_t)((h0 + yy) * PH + (w0 + xx)) * (C_IN * 2)
                                 + (((s ^ p) & 7) << 4);
            GLOAD_LDS(gp, (char*)dst + r * 7168 + wave * 1024);
        }
        if (tid < 64) {                      // wave 0 exactly (wave-uniform)
            int chunk = 5 * 448 + tid;       // 2240..2303
            int p = chunk >> 3, s = chunk & 7;
            int yy = p / BH_X, xx = p - yy * BH_X;
            const char* gp = xTb + (size_t)((h0 + yy) * PH + (w0 + xx)) * (C_IN * 2)
                                 + (((s ^ p) & 7) << 4);
            GLOAD_LDS(gp, (char*)dst + 5 * 7168 + wave * 1024);
        }
    };

    // per-lane pixel in tile: wave owns rows {2w, 2w+1}, cols 0..15
    const int py = 2 * wave + (ln >> 4);
    const int px = ln & 15;

    // bias by accumulator slot, o = mh*64 + mt*32 + mloc
    float bv[2][16];
    #pragma unroll
    for (int mt = 0; mt < 2; ++mt)
        #pragma unroll
        for (int r = 0; r < 16; ++r) {
            int mloc = (r & 3) + 8 * (r >> 2) + 4 * g;
            bv[mt][r] = bias[mh * 64 + mt * 32 + mloc];
        }

    STAGE(0, Bs0);
    __syncthreads();   // drain A + B0

    const size_t outb = (size_t)b * C_OUT * NPIX;

    #pragma unroll 1
    for (int it = 0; it < 7; ++it) {
        unsigned char* curB = (it & 1) ? Bs1 : Bs0;
        unsigned char* nxtB = (it & 1) ? Bs0 : Bs1;
        if (it < 6) STAGE(it + 1, nxtB);   // async; completes during compute

        f32x16 acc[2];
        #pragma unroll
        for (int mt = 0; mt < 2; ++mt)
            #pragma unroll
            for (int r = 0; r < 16; ++r) acc[mt][r] = bv[mt][r];

        #pragma unroll
        for (int t = 0; t < NSTEPS; ++t) {
            const int ij = t >> 2, cs = t & 3;
            const int di = ij / 3, dj = ij - di * 3;
            const int jb = cs * 2 + g;
            bf16x8 a0 = __builtin_bit_cast(bf16x8,
                *(const uint4*)(As + ((t * 2 + 0) * 64 + l) * 16));
            bf16x8 a1 = __builtin_bit_cast(bf16x8,
                *(const uint4*)(As + ((t * 2 + 1) * 64 + l) * 16));
            const int Pa = (py + di) * BH_X + (px + dj);
            bf16x8 bb = __builtin_bit_cast(bf16x8,
                *(const uint4*)(curB + Pa * 128 + (((jb ^ Pa) & 7) << 4)));
            acc[0] = __builtin_amdgcn_mfma_f32_32x32x16_bf16(a0, bb, acc[0], 0, 0, 0);
            acc[1] = __builtin_amdgcn_mfma_f32_32x32x16_bf16(a1, bb, acc[1], 0, 0, 0);
        }

        // ---- stores: C/D col=lane&31 (pixel), row=(r&3)+8*(r>>2)+4*g ----
        #pragma unroll
        for (int mt = 0; mt < 2; ++mt)
            #pragma unroll
            for (int r = 0; r < 16; ++r) {
                int mloc = (r & 3) + 8 * (r >> 2) + 4 * g;
                int o = mh * 64 + mt * 32 + mloc;
                out[outb + (size_t)o * NPIX + (h0 + py) * WW + it * 16 + px] = acc[mt][r];
            }

        if (it < 6) __syncthreads();   // drains stage vmcnt; next iter reads nxtB
    }
}

// ---------------- fallback (round-2 kernel) if ws too small for xT ----------------
__global__ __launch_bounds__(256, 4) void sparse_conv_fb_kernel(
        const float* __restrict__ x, const unsigned short* __restrict__ pw,
        const float* __restrict__ bias, float* __restrict__ out) {
    __shared__ __align__(16) unsigned short xs[HALO_P * C_IN];

    const int bid = blockIdx.x;
    const int b   = bid / NTILES;
    const int t98 = bid % NTILES;
    const int tyi = t98 / TILES_X;
    const int txi = t98 % TILES_X;
    const int h0  = tyi * TY, w0 = txi * TX;
    const int tid = threadIdx.x;

    const float* xb = x + (size_t)b * C_IN * HH * WW;
    {
        const int p  = tid;
        const bool act = p < HALO_P;
        int yy = p / HALO_X;
        int xx = p - yy * HALO_X;
        int gh = h0 + yy - 1, gw = w0 + xx - 1;
        const bool valid = act && (unsigned)gh < (unsigned)HH && (unsigned)gw < (unsigned)WW;
        const float* bp = xb + (gh * WW + gw);
        float v[C_IN];
        #pragma unroll
        for (int c = 0; c < C_IN; ++c)
            v[c] = valid ? bp[c * (HH * WW)] : 0.0f;
        if (act) {
            char* xc = (char*)xs + p * (C_IN * 2);
            #pragma unroll
            for (int j = 0; j < 8; ++j) {
                bf16x8 bvv;
                #pragma unroll
                for (int e = 0; e < 8; ++e) bvv[e] = (__bf16)v[j * 8 + e];
                *(uint4*)(xc + (((j ^ p) & 7) << 4)) = __builtin_bit_cast(uint4, bvv);
            }
        }
    }
    __syncthreads();

    const int wave = tid >> 6, l = tid & 63;
    const int wm = wave >> 1, wn = wave & 1;
    const int g  = l >> 5,  ln = l & 31;

    int P0[2];
    #pragma unroll
    for (int ntp = 0; ntp < 2; ++ntp) {
        int pt = wn * 64 + ntp * 32 + ln;
        P0[ntp] = (pt >> 4) * HALO_X + (pt & 15);
    }

    f32x16 acc[2][2];
    #pragma unroll
    for (int i = 0; i < 2; ++i)
        #pragma unroll
        for (int jq = 0; jq < 2; ++jq)
            #pragma unroll
            for (int q = 0; q < 16; ++q) acc[i][jq][q] = 0.0f;

    const uint4* __restrict__ pwv = (const uint4*)pw;

    #pragma unroll 1
    for (int ij = 0; ij < 9; ++ij) {
        const int di = ij / 3;
        const int dj = ij - di * 3;
        const int P0a = P0[0] + di * HALO_X + dj;
        const int P1a = P0[1] + di * HALO_X + dj;
        #pragma unroll
        for (int cs = 0; cs < 4; ++cs) {
            const int t = ij * 4 + cs;
            bf16x8 a0 = __builtin_bit_cast(bf16x8, pwv[(t * 4 + wm * 2 + 0) * 64 + l]);
            bf16x8 a1 = __builtin_bit_cast(bf16x8, pwv[(t * 4 + wm * 2 + 1) * 64 + l]);
            const int jb = cs * 2 + g;
            bf16x8 b0 = __builtin_bit_cast(bf16x8,
                *(const uint4*)((const char*)xs + P0a * (C_IN * 2) + (((jb ^ P0a) & 7) << 4)));
            bf16x8 b1 = __builtin_bit_cast(bf16x8,
                *(const uint4*)((const char*)xs + P1a * (C_IN * 2) + (((jb ^ P1a) & 7) << 4)));
            acc[0][0] = __builtin_amdgcn_mfma_f32_32x32x16_bf16(a0, b0, acc[0][0], 0, 0, 0);
            acc[0][1] = __builtin_amdgcn_mfma_f32_32x32x16_bf16(a0, b1, acc[0][1], 0, 0, 0);
            acc[1][0] = __builtin_amdgcn_mfma_f32_32x32x16_bf16(a1, b0, acc[1][0], 0, 0, 0);
            acc[1][1] = __builtin_amdgcn_mfma_f32_32x32x16_bf16(a1, b1, acc[1][1], 0, 0, 0);
        }
    }

    const size_t outb = (size_t)b * C_OUT * HH * WW;
    #pragma unroll
    for (int mtp = 0; mtp < 2; ++mtp) {
        #pragma unroll
        for (int r = 0; r < 16; ++r) {
            int mloc = (r & 3) + 8 * (r >> 2) + 4 * g;
            int o = (wm * 2 + mtp) * 32 + mloc;
            float bvv = bias[o];
            #pragma unroll
            for (int ntp = 0; ntp < 2; ++ntp) {
                int p  = wn * 64 + ntp * 32 + ln;
                int gh = h0 + (p >> 4), gw = w0 + (p & 15);
                out[outb + ((size_t)o * HH + gh) * WW + gw] = acc[mtp][ntp][r] + bvv;
            }
        }
    }
}

extern "C" void kernel_launch(void* const* d_in, const int* in_sizes, int n_in,
                              void* d_out, int out_size, void* d_ws, size_t ws_size,
                              hipStream_t stream) {
    const float* x    = (const float*)d_in[0];
    const float* w    = (const float*)d_in[1];
    const float* mk   = (const float*)d_in[2];
    const float* bs   = (const float*)d_in[3];
    float* out        = (float*)d_out;
    unsigned short* pw = (unsigned short*)d_ws;   // [0, 147456)

    pack_w_kernel<<<dim3(NSTEPS), dim3(256), 0, stream>>>(w, mk, pw);

    if (ws_size >= (size_t)XT_OFF + XT_BYTES) {
        unsigned short* xT = (unsigned short*)((char*)d_ws + XT_OFF);
        transpose_x_kernel<<<dim3((PPIX + 255) / 256, NB), dim3(256), 0, stream>>>(x, xT);
        sparse_conv_band_kernel<<<dim3(256), dim3(448), 0, stream>>>(xT, pw, bs, out);
    } else {
        sparse_conv_fb_kernel<<<dim3(NB * NTILES), dim3(256), 0, stream>>>(x, pw, bs, out);
    }
}